// Round 13
// baseline (951.337 us; speedup 1.0000x reference)
//
#include <hip/hip_runtime.h>
#include <math.h>

#define N_NODES 50000
#define N_EDGES 800000
#define IN_CH 128
#define HID 256
#define OUT_CH 40

#define CAP 64          // fixed slots per node (deg~Poisson(16), max ~35)
#define OV_CAP 65536    // overflow safety net (correctness only)
#define NB 64           // fill blocks; each owns ceil(N/NB) nodes
#define NPB ((N_NODES + NB - 1) / NB)   // 782

typedef __attribute__((ext_vector_type(8))) short short8;
typedef __attribute__((ext_vector_type(4))) float floatx4;
typedef __attribute__((ext_vector_type(2))) float floatx2;

__device__ __forceinline__ unsigned short f2bf(float f) {
    unsigned int u = __float_as_uint(f);
    u += 0x7fff + ((u >> 16) & 1);
    return (unsigned short)(u >> 16);
}
__device__ __forceinline__ float bf2f(unsigned short h) {
    return __uint_as_float(((unsigned int)h) << 16);
}

// ---- fp8 e4m3fn (OCP) encode/decode (unbiased RNE) ----
__device__ __forceinline__ unsigned char f2fp8(float f) {
    f = fminf(448.f, fmaxf(-448.f, f));
    unsigned u = __float_as_uint(f);
    unsigned s = (u >> 24) & 0x80u;
    u &= 0x7fffffffu;
    if (u < 0x3c800000u) return (unsigned char)s;   // flush |f| < 2^-6
    unsigned r = u + 0x7FFFFu + ((u >> 20) & 1u);   // unbiased RNE
    unsigned em = (r >> 20) - 960u;
    return (unsigned char)(s | em);
}

__device__ __forceinline__ void fp8x4_to_f32x4(unsigned int q, float* o) {
#if defined(__has_builtin) && __has_builtin(__builtin_amdgcn_cvt_pk_f32_fp8)
    floatx2 lo = __builtin_amdgcn_cvt_pk_f32_fp8((int)q, false);
    floatx2 hi = __builtin_amdgcn_cvt_pk_f32_fp8((int)q, true);
    o[0] = lo.x; o[1] = lo.y; o[2] = hi.x; o[3] = hi.y;
#else
#pragma unroll
    for (int i = 0; i < 4; ++i) {
        unsigned b = (q >> (8 * i)) & 0xffu;
        unsigned em = b & 0x7fu;
        unsigned bits = em ? (((b & 0x80u) << 24) | ((em << 20) + (120u << 23)))
                           : ((b & 0x80u) << 24);
        o[i] = __uint_as_float(bits);
    }
#endif
}

// ============== CSR build: one block owns one node range ====================
// LDS counters (no global atomics); each node's 512B slot region is written by
// exactly one CU -> lines assemble in its XCD L2. dst scanned via int4 loads.
__global__ __launch_bounds__(256) void fill_block(const int4* __restrict__ dst4,
                                                  const int* __restrict__ src,
                                                  const float* __restrict__ ew,
                                                  int* __restrict__ cnt,
                                                  int2* __restrict__ csr,
                                                  int4* __restrict__ ov,
                                                  int* __restrict__ ov_cnt) {
    __shared__ int lcnt[NPB];
    const int lo = blockIdx.x * NPB;
    const int hi = min(N_NODES, lo + NPB);
    const int nloc = hi - lo;
    for (int i = threadIdx.x; i < nloc; i += 256) lcnt[i] = 0;
    __syncthreads();
    const int total4 = N_EDGES / 4;
    for (int e4 = threadIdx.x; e4 < total4; e4 += 256) {
        int4 d4 = dst4[e4];
        int e = e4 * 4;
#pragma unroll
        for (int k = 0; k < 4; ++k) {
            int d = (k == 0) ? d4.x : (k == 1) ? d4.y : (k == 2) ? d4.z : d4.w;
            if (d >= lo && d < hi) {
                int slot = atomicAdd(&lcnt[d - lo], 1);
                if (slot < CAP) {
                    csr[(size_t)d * CAP + slot] =
                        make_int2(src[e + k], __float_as_int(ew[e + k]));
                } else {
                    int oi = atomicAdd(ov_cnt, 1);
                    if (oi < OV_CAP)
                        ov[oi] = make_int4(src[e + k], __float_as_int(ew[e + k]), d, 0);
                }
            }
        }
    }
    __syncthreads();
    for (int i = threadIdx.x; i < nloc; i += 256) cnt[lo + i] = lcnt[i];
}

// ------------- all three weight casts fused: Wt[m][k] = bf16(W[k][m]) ------
__global__ __launch_bounds__(256) void wt_cast_all(const float* __restrict__ W1,
                                                   const float* __restrict__ W2,
                                                   const float* __restrict__ W3,
                                                   short* __restrict__ Wt1,
                                                   short* __restrict__ Wt2,
                                                   short* __restrict__ Wt3) {
    int idx = blockIdx.x * 256 + threadIdx.x;
    const int n1 = IN_CH * HID, n2 = HID * HID, n3 = HID * OUT_CH;
    if (idx < n1) {
        int m = idx / IN_CH, k = idx - m * IN_CH;
        Wt1[idx] = (short)f2bf(W1[(size_t)k * HID + m]);
    } else if (idx < n1 + n2) {
        int j = idx - n1;
        int m = j / HID, k = j - m * HID;
        Wt2[j] = (short)f2bf(W2[(size_t)k * HID + m]);
    } else if (idx < n1 + n2 + n3) {
        int j = idx - n1 - n2;
        int m = j / HID, k = j - m * HID;
        Wt3[j] = (short)f2bf(W3[(size_t)k * OUT_CH + m]);
    }
}

__global__ __launch_bounds__(256) void cast_x_fp8(const float4* __restrict__ x4,
                                                  uchar4* __restrict__ xq,
                                                  int total4) {
    int i = blockIdx.x * 256 + threadIdx.x;
    if (i >= total4) return;
    float4 v = x4[i];
    xq[i] = make_uchar4(f2fp8(v.x), f2fp8(v.y), f2fp8(v.z), f2fp8(v.w));
}

// -------- gather layer1: agg(x fp8) -> bf16, 32 thr/node x 4 feats ---------
__global__ __launch_bounds__(256) void gather_x_fp8(const unsigned char* __restrict__ xq,
                                                    const int* __restrict__ cnt,
                                                    const int2* __restrict__ csr,
                                                    const int4* __restrict__ ov,
                                                    const int* __restrict__ ov_cnt,
                                                    unsigned short* __restrict__ out) {
    int node = blockIdx.x * 8 + (threadIdx.x >> 5);
    int g = threadIdx.x & 31;
    if (node >= N_NODES) return;
    int beg = node * CAP;
    int end = beg + min(cnt[node], CAP);
    float a[4] = {};
    for (int base = beg; base < end; base += 32) {
        int c = min(32, end - base);
        int sv = 0; float wv = 0.f;
        if (g < c) {
            int2 iv = csr[base + g];
            sv = iv.x; wv = __int_as_float(iv.y);
        }
        int j = 0;
        for (; j + 4 <= c; j += 4) {
            int s0 = __shfl(sv, j, 32),     s1 = __shfl(sv, j + 1, 32);
            int s2 = __shfl(sv, j + 2, 32), s3 = __shfl(sv, j + 3, 32);
            float w0 = __shfl(wv, j, 32),     w1 = __shfl(wv, j + 1, 32);
            float w2 = __shfl(wv, j + 2, 32), w3 = __shfl(wv, j + 3, 32);
            unsigned q0 = *(const unsigned*)(xq + (size_t)s0 * 128 + g * 4);
            unsigned q1 = *(const unsigned*)(xq + (size_t)s1 * 128 + g * 4);
            unsigned q2 = *(const unsigned*)(xq + (size_t)s2 * 128 + g * 4);
            unsigned q3 = *(const unsigned*)(xq + (size_t)s3 * 128 + g * 4);
            float d0[4], d1[4], d2[4], d3[4];
            fp8x4_to_f32x4(q0, d0); fp8x4_to_f32x4(q1, d1);
            fp8x4_to_f32x4(q2, d2); fp8x4_to_f32x4(q3, d3);
#pragma unroll
            for (int t = 0; t < 4; ++t)
                a[t] += d0[t] * w0 + d1[t] * w1 + d2[t] * w2 + d3[t] * w3;
        }
        for (; j < c; ++j) {
            int s0 = __shfl(sv, j, 32);
            float w0 = __shfl(wv, j, 32);
            unsigned q0 = *(const unsigned*)(xq + (size_t)s0 * 128 + g * 4);
            float d0[4];
            fp8x4_to_f32x4(q0, d0);
#pragma unroll
            for (int t = 0; t < 4; ++t) a[t] += d0[t] * w0;
        }
    }
    int L = min(*ov_cnt, OV_CAP);
    for (int i = 0; i < L; ++i) {
        int4 e = ov[i];
        if (e.z == node) {
            float w0 = __int_as_float(e.y);
            unsigned q0 = *(const unsigned*)(xq + (size_t)e.x * 128 + g * 4);
            float d0[4];
            fp8x4_to_f32x4(q0, d0);
#pragma unroll
            for (int t = 0; t < 4; ++t) a[t] += d0[t] * w0;
        }
    }
    ushort4 o = make_ushort4(f2bf(a[0]), f2bf(a[1]), f2bf(a[2]), f2bf(a[3]));
    *(ushort4*)(out + (size_t)node * 128 + g * 4) = o;
}

// ---- gather layer2: agg(h fp8) -> bias+relu -> bf16, 32 thr/node x 8 ------
__global__ __launch_bounds__(256) void gather_h_fp8(const unsigned char* __restrict__ h,
                                                    const int* __restrict__ cnt,
                                                    const int2* __restrict__ csr,
                                                    const int4* __restrict__ ov,
                                                    const int* __restrict__ ov_cnt,
                                                    const float* __restrict__ bias,
                                                    unsigned short* __restrict__ out) {
    int node = blockIdx.x * 8 + (threadIdx.x >> 5);
    int g = threadIdx.x & 31;
    if (node >= N_NODES) return;
    int beg = node * CAP;
    int end = beg + min(cnt[node], CAP);
    float acc[8] = {};
    for (int base = beg; base < end; base += 32) {
        int c = min(32, end - base);
        int sv = 0; float wv = 0.f;
        if (g < c) {
            int2 iv = csr[base + g];
            sv = iv.x; wv = __int_as_float(iv.y);
        }
        int j = 0;
        for (; j + 4 <= c; j += 4) {
            int s0 = __shfl(sv, j, 32),     s1 = __shfl(sv, j + 1, 32);
            int s2 = __shfl(sv, j + 2, 32), s3 = __shfl(sv, j + 3, 32);
            float w0 = __shfl(wv, j, 32),     w1 = __shfl(wv, j + 1, 32);
            float w2 = __shfl(wv, j + 2, 32), w3 = __shfl(wv, j + 3, 32);
            uint2 q0 = *(const uint2*)(h + (size_t)s0 * 256 + g * 8);
            uint2 q1 = *(const uint2*)(h + (size_t)s1 * 256 + g * 8);
            uint2 q2 = *(const uint2*)(h + (size_t)s2 * 256 + g * 8);
            uint2 q3 = *(const uint2*)(h + (size_t)s3 * 256 + g * 8);
            float d0[8], d1[8], d2[8], d3[8];
            fp8x4_to_f32x4(q0.x, d0); fp8x4_to_f32x4(q0.y, d0 + 4);
            fp8x4_to_f32x4(q1.x, d1); fp8x4_to_f32x4(q1.y, d1 + 4);
            fp8x4_to_f32x4(q2.x, d2); fp8x4_to_f32x4(q2.y, d2 + 4);
            fp8x4_to_f32x4(q3.x, d3); fp8x4_to_f32x4(q3.y, d3 + 4);
#pragma unroll
            for (int t = 0; t < 8; ++t)
                acc[t] += d0[t] * w0 + d1[t] * w1 + d2[t] * w2 + d3[t] * w3;
        }
        for (; j < c; ++j) {
            int s0 = __shfl(sv, j, 32);
            float w0 = __shfl(wv, j, 32);
            uint2 q0 = *(const uint2*)(h + (size_t)s0 * 256 + g * 8);
            float d0[8];
            fp8x4_to_f32x4(q0.x, d0); fp8x4_to_f32x4(q0.y, d0 + 4);
#pragma unroll
            for (int t = 0; t < 8; ++t)
                acc[t] += d0[t] * w0;
        }
    }
    int L = min(*ov_cnt, OV_CAP);
    for (int i = 0; i < L; ++i) {
        int4 e = ov[i];
        if (e.z == node) {
            float w0 = __int_as_float(e.y);
            uint2 q0 = *(const uint2*)(h + (size_t)e.x * 256 + g * 8);
            float d0[8];
            fp8x4_to_f32x4(q0.x, d0); fp8x4_to_f32x4(q0.y, d0 + 4);
#pragma unroll
            for (int t = 0; t < 8; ++t) acc[t] += d0[t] * w0;
        }
    }
    short8 ov8;
#pragma unroll
    for (int t = 0; t < 8; ++t) {
        float r = fmaxf(acc[t] + bias[g * 8 + t], 0.f);
        ov8[t] = (short)f2bf(r);
    }
    *(short8*)(out + (size_t)node * 256 + g * 8) = ov8;
}

// --------------- bf16 MFMA GEMM: C[N,M] = A[N,K] @ Wt[M,K]^T ---------------
// BM=128, BN=64, BK=32; 4 waves (2x2); OUT_MODE: 0=f32, 1=bf16, 2=fp8
template <int OUT_MODE>
__global__ __launch_bounds__(256) void mfma_gemm(const short* __restrict__ A,
                                                 const short* __restrict__ Wt,
                                                 void* __restrict__ Cout,
                                                 int N, int K, int M,
                                                 const float* __restrict__ bias,
                                                 int act) {
    __shared__ short As[128 * 32];
    __shared__ short Bs[64 * 32];
    const int tid = threadIdx.x;
    const int lane = tid & 63;
    const int wave = tid >> 6;
    const int wr = wave >> 1, wc = wave & 1;
    const int row0 = blockIdx.y * 128;
    const int col0 = blockIdx.x * 64;

    floatx4 acc[4][2];
#pragma unroll
    for (int t = 0; t < 4; ++t)
#pragma unroll
        for (int u = 0; u < 2; ++u) acc[t][u] = (floatx4){0.f, 0.f, 0.f, 0.f};

    for (int k0 = 0; k0 < K; k0 += 32) {
#pragma unroll
        for (int i = 0; i < 2; ++i) {
            int idx = tid + i * 256;
            int r = idx >> 2, ch = idx & 3;
            int gr = row0 + r;
            int4 v = make_int4(0, 0, 0, 0);
            if (gr < N) v = *(const int4*)(A + (size_t)gr * K + k0 + ch * 8);
            *(int4*)&As[r * 32 + ((ch ^ ((r >> 1) & 3)) << 3)] = v;
        }
        {
            int r = tid >> 2, ch = tid & 3;
            int gn = col0 + r;
            int4 v = make_int4(0, 0, 0, 0);
            if (gn < M) v = *(const int4*)(Wt + (size_t)gn * K + k0 + ch * 8);
            *(int4*)&Bs[r * 32 + ((ch ^ ((r >> 1) & 3)) << 3)] = v;
        }
        __syncthreads();

        short8 bf[2];
#pragma unroll
        for (int u = 0; u < 2; ++u) {
            int n = wc * 32 + u * 16 + (lane & 15);
            int ch = (lane >> 4) ^ ((n >> 1) & 3);
            bf[u] = *(const short8*)&Bs[n * 32 + (ch << 3)];
        }
#pragma unroll
        for (int t = 0; t < 4; ++t) {
            int r = wr * 64 + t * 16 + (lane & 15);
            int ch = (lane >> 4) ^ ((r >> 1) & 3);
            short8 af = *(const short8*)&As[r * 32 + (ch << 3)];
            acc[t][0] = __builtin_amdgcn_mfma_f32_16x16x32_bf16(af, bf[0], acc[t][0], 0, 0, 0);
            acc[t][1] = __builtin_amdgcn_mfma_f32_16x16x32_bf16(af, bf[1], acc[t][1], 0, 0, 0);
        }
        __syncthreads();
    }

#pragma unroll
    for (int t = 0; t < 4; ++t) {
#pragma unroll
        for (int u = 0; u < 2; ++u) {
            int gcol = col0 + wc * 32 + u * 16 + (lane & 15);
            if (gcol >= M) continue;
            float bv = bias ? bias[gcol] : 0.f;
#pragma unroll
            for (int reg = 0; reg < 4; ++reg) {
                int grow = row0 + wr * 64 + t * 16 + (lane >> 4) * 4 + reg;
                if (grow >= N) continue;
                float v = acc[t][u][reg] + bv;
                if (act) v = fmaxf(v, 0.f);
                if (OUT_MODE == 1)
                    ((unsigned short*)Cout)[(size_t)grow * M + gcol] = f2bf(v);
                else if (OUT_MODE == 2)
                    ((unsigned char*)Cout)[(size_t)grow * M + gcol] = f2fp8(v);
                else
                    ((float*)Cout)[(size_t)grow * M + gcol] = v;
            }
        }
    }
}

// ---- final: gather bf16 40-wide rows + bias + log_softmax, wave/node ------
__global__ __launch_bounds__(256) void gather_lsm(const unsigned short* __restrict__ h,
                                                  const int* __restrict__ cnt,
                                                  const int2* __restrict__ csr,
                                                  const int4* __restrict__ ov,
                                                  const int* __restrict__ ov_cnt,
                                                  const float* __restrict__ b,
                                                  float* __restrict__ out, int n) {
    int wave = threadIdx.x >> 6;
    int lane = threadIdx.x & 63;
    int node = blockIdx.x * 4 + wave;
    if (node >= n) return;
    int beg = node * CAP;
    int end = beg + min(cnt[node], CAP);
    float acc = 0.f;
    for (int base = beg; base < end; base += 64) {
        int c = min(64, end - base);
        int sv = 0; float wv = 0.f;
        if (lane < c) {
            int2 iv = csr[base + lane];
            sv = iv.x; wv = __int_as_float(iv.y);
        }
        int j = 0;
        for (; j + 4 <= c; j += 4) {
            int s0 = __shfl(sv, j, 64),     s1 = __shfl(sv, j + 1, 64);
            int s2 = __shfl(sv, j + 2, 64), s3 = __shfl(sv, j + 3, 64);
            float w0 = __shfl(wv, j, 64),     w1 = __shfl(wv, j + 1, 64);
            float w2 = __shfl(wv, j + 2, 64), w3 = __shfl(wv, j + 3, 64);
            float v0 = 0.f, v1 = 0.f, v2 = 0.f, v3 = 0.f;
            if (lane < OUT_CH) {
                v0 = bf2f(h[(size_t)s0 * OUT_CH + lane]);
                v1 = bf2f(h[(size_t)s1 * OUT_CH + lane]);
                v2 = bf2f(h[(size_t)s2 * OUT_CH + lane]);
                v3 = bf2f(h[(size_t)s3 * OUT_CH + lane]);
            }
            acc += v0 * w0 + v1 * w1 + v2 * w2 + v3 * w3;
        }
        for (; j < c; ++j) {
            int s0 = __shfl(sv, j, 64);
            float w0 = __shfl(wv, j, 64);
            if (lane < OUT_CH) acc += bf2f(h[(size_t)s0 * OUT_CH + lane]) * w0;
        }
    }
    int L = min(*ov_cnt, OV_CAP);
    for (int i = 0; i < L; ++i) {
        int4 e = ov[i];
        if (e.z == node && lane < OUT_CH)
            acc += bf2f(h[(size_t)e.x * OUT_CH + lane]) * __int_as_float(e.y);
    }
    float val = 0.f, v = -INFINITY;
    if (lane < OUT_CH) {
        val = acc + b[lane];
        v = val;
    }
#pragma unroll
    for (int off = 32; off; off >>= 1)
        v = fmaxf(v, __shfl_xor(v, off, 64));
    float ex = (lane < OUT_CH) ? expf(val - v) : 0.f;
#pragma unroll
    for (int off = 32; off; off >>= 1)
        ex += __shfl_xor(ex, off, 64);
    float ls = logf(ex);
    if (lane < OUT_CH) out[(size_t)node * OUT_CH + lane] = val - v - ls;
}

// ---------------------------------------------------------------------------
extern "C" void kernel_launch(void* const* d_in, const int* in_sizes, int n_in,
                              void* d_out, int out_size, void* d_ws, size_t ws_size,
                              hipStream_t stream) {
    const float* x   = (const float*)d_in[0];
    const int*  eidx = (const int*)d_in[1];
    const float* ew  = (const float*)d_in[2];
    const float* W1  = (const float*)d_in[3];
    const float* b1  = (const float*)d_in[4];
    const float* W2  = (const float*)d_in[5];
    const float* b2  = (const float*)d_in[6];
    const float* W3  = (const float*)d_in[7];
    const float* b3  = (const float*)d_in[8];
    const int* src = eidx;
    const int* dst = eidx + N_EDGES;
    float* out = (float*)d_out;

    short* region0 = (short*)d_ws;                          // xq(fp8) / h2p(fp8)
    short* region1 = region0 + (size_t)N_NODES * HID;       // aggX / h3p
    short* H1   = region1 + (size_t)N_NODES * IN_CH;
    short* H2   = H1 + (size_t)N_NODES * HID;
    short* Wt1  = H2 + (size_t)N_NODES * HID;
    short* Wt2  = Wt1 + HID * IN_CH;
    short* Wt3  = Wt2 + HID * HID;
    int*   cnt     = (int*)(Wt3 + OUT_CH * HID);            // N_NODES + 1 (ov_cnt)
    int*   ov_cnt  = cnt + N_NODES;
    int2*  csr     = (int2*)(cnt + N_NODES + 2);            // N_NODES*CAP int2
    int4*  ovbuf   = (int4*)(csr + (size_t)N_NODES * CAP);  // OV_CAP int4

    unsigned char* xq  = (unsigned char*)region0;           // fp8, 6.4 MB
    unsigned char* h2p = (unsigned char*)region0;           // fp8, 12.8 MB
    short* aggX = region1;
    short* h3p  = region1;

    dim3 blk(256);

    // ---- CSR build: zero ov_cnt, one edge pass with LDS counters
    hipMemsetAsync(ov_cnt, 0, sizeof(int), stream);
    fill_block<<<NB, blk, 0, stream>>>((const int4*)dst, src, ew, cnt, csr, ovbuf, ov_cnt);

    // ---- weight + x casts
    {
        int tot = IN_CH * HID + HID * HID + HID * OUT_CH;
        wt_cast_all<<<(tot + 255) / 256, blk, 0, stream>>>(W1, W2, W3, Wt1, Wt2, Wt3);
    }
    cast_x_fp8<<<(N_NODES * IN_CH / 4 + 255) / 256, blk, 0, stream>>>(
        (const float4*)x, (uchar4*)xq, N_NODES * IN_CH / 4);

    // ---- layer 1 (swapped): aggX = gather(xq); H1 = relu(aggX@W1 + b1)
    gather_x_fp8<<<(N_NODES + 7) / 8, blk, 0, stream>>>(
        xq, cnt, csr, ovbuf, ov_cnt, (unsigned short*)aggX);
    {
        dim3 grid((HID + 63) / 64, (N_NODES + 127) / 128);
        mfma_gemm<1><<<grid, blk, 0, stream>>>(aggX, Wt1, H1, N_NODES, IN_CH, HID, b1, 1);
    }

    // ---- layer 2: h2p = fp8(H1@W2) ; H2 = relu(gather(h2p) + b2)
    {
        dim3 grid((HID + 63) / 64, (N_NODES + 127) / 128);
        mfma_gemm<2><<<grid, blk, 0, stream>>>(H1, Wt2, h2p, N_NODES, HID, HID, nullptr, 0);
    }
    gather_h_fp8<<<(N_NODES + 7) / 8, blk, 0, stream>>>(
        h2p, cnt, csr, ovbuf, ov_cnt, b2, (unsigned short*)H2);

    // ---- layer 3: h3p = H2@W3 (bf16) ; out = log_softmax(gather(h3p) + b3)
    {
        dim3 grid((OUT_CH + 63) / 64, (N_NODES + 127) / 128);
        mfma_gemm<1><<<grid, blk, 0, stream>>>(H2, Wt3, h3p, N_NODES, HID, OUT_CH, nullptr, 0);
    }
    gather_lsm<<<(N_NODES + 3) / 4, blk, 0, stream>>>(
        (const unsigned short*)h3p, cnt, csr, ovbuf, ov_cnt, b3, out, N_NODES);
}

// Round 14
// 282.369 us; speedup vs baseline: 3.3691x; 3.3691x over previous
//
#include <hip/hip_runtime.h>
#include <math.h>

#define N_NODES 50000
#define N_EDGES 800000
#define IN_CH 128
#define HID 256
#define OUT_CH 40

#define PARTS 8
#define PART_SIZE ((N_NODES + PARTS - 1) / PARTS)   // 6250
#define NCHUNK 128
#define CAP 64          // fixed slots per node (deg~Poisson(16), max ~35)
#define OV_CAP 65536    // overflow safety net (correctness only)

typedef __attribute__((ext_vector_type(8))) short short8;
typedef __attribute__((ext_vector_type(4))) float floatx4;
typedef __attribute__((ext_vector_type(2))) float floatx2;

typedef __attribute__((address_space(3))) void lds_void;
typedef const __attribute__((address_space(1))) void glb_void;

__device__ __forceinline__ unsigned short f2bf(float f) {
    unsigned int u = __float_as_uint(f);
    u += 0x7fff + ((u >> 16) & 1);
    return (unsigned short)(u >> 16);
}
__device__ __forceinline__ float bf2f(unsigned short h) {
    return __uint_as_float(((unsigned int)h) << 16);
}

// ---- fp8 e4m3fn (OCP) encode/decode (unbiased RNE) ----
__device__ __forceinline__ unsigned char f2fp8(float f) {
    f = fminf(448.f, fmaxf(-448.f, f));
    unsigned u = __float_as_uint(f);
    unsigned s = (u >> 24) & 0x80u;
    u &= 0x7fffffffu;
    if (u < 0x3c800000u) return (unsigned char)s;   // flush |f| < 2^-6
    unsigned r = u + 0x7FFFFu + ((u >> 20) & 1u);   // unbiased RNE
    unsigned em = (r >> 20) - 960u;
    return (unsigned char)(s | em);
}

__device__ __forceinline__ void fp8x4_to_f32x4(unsigned int q, float* o) {
#if defined(__has_builtin) && __has_builtin(__builtin_amdgcn_cvt_pk_f32_fp8)
    floatx2 lo = __builtin_amdgcn_cvt_pk_f32_fp8((int)q, false);
    floatx2 hi = __builtin_amdgcn_cvt_pk_f32_fp8((int)q, true);
    o[0] = lo.x; o[1] = lo.y; o[2] = hi.x; o[3] = hi.y;
#else
#pragma unroll
    for (int i = 0; i < 4; ++i) {
        unsigned b = (q >> (8 * i)) & 0xffu;
        unsigned em = b & 0x7fu;
        unsigned bits = em ? (((b & 0x80u) << 24) | ((em << 20) + (120u << 23)))
                           : ((b & 0x80u) << 24);
        o[i] = __uint_as_float(bits);
    }
#endif
}

// ============== CSR build: single pass, fixed capacity (r12) ===============
__global__ __launch_bounds__(256) void fill_fixed(const int* __restrict__ src,
                                                  const int* __restrict__ dst,
                                                  const float* __restrict__ ew,
                                                  int* __restrict__ cnt,
                                                  int2* __restrict__ csr,
                                                  int4* __restrict__ ov,
                                                  int* __restrict__ ov_cnt) {
    int part = blockIdx.x & (PARTS - 1);
    int chunk = blockIdx.x >> 3;
    int lo = part * PART_SIZE, hi = min(N_NODES, lo + PART_SIZE);
    const int per = (N_EDGES + NCHUNK - 1) / NCHUNK;
    int beg = chunk * per, end = min(N_EDGES, beg + per);
    for (int e = beg + (int)threadIdx.x; e < end; e += 256) {
        int d = dst[e];
        if (d >= lo && d < hi) {
            int slot = atomicAdd(&cnt[d], 1);
            if (slot < CAP) {
                csr[(size_t)d * CAP + slot] = make_int2(src[e], __float_as_int(ew[e]));
            } else {
                int oi = atomicAdd(ov_cnt, 1);
                if (oi < OV_CAP)
                    ov[oi] = make_int4(src[e], __float_as_int(ew[e]), d, 0);
            }
        }
    }
}

// ------------- all three weight casts fused: Wt[m][k] = bf16(W[k][m]) ------
__global__ __launch_bounds__(256) void wt_cast_all(const float* __restrict__ W1,
                                                   const float* __restrict__ W2,
                                                   const float* __restrict__ W3,
                                                   short* __restrict__ Wt1,
                                                   short* __restrict__ Wt2,
                                                   short* __restrict__ Wt3) {
    int idx = blockIdx.x * 256 + threadIdx.x;
    const int n1 = IN_CH * HID, n2 = HID * HID, n3 = HID * OUT_CH;
    if (idx < n1) {
        int m = idx / IN_CH, k = idx - m * IN_CH;
        Wt1[idx] = (short)f2bf(W1[(size_t)k * HID + m]);
    } else if (idx < n1 + n2) {
        int j = idx - n1;
        int m = j / HID, k = j - m * HID;
        Wt2[j] = (short)f2bf(W2[(size_t)k * HID + m]);
    } else if (idx < n1 + n2 + n3) {
        int j = idx - n1 - n2;
        int m = j / HID, k = j - m * HID;
        Wt3[j] = (short)f2bf(W3[(size_t)k * OUT_CH + m]);
    }
}

__global__ __launch_bounds__(256) void cast_x_fp8(const float4* __restrict__ x4,
                                                  uchar4* __restrict__ xq,
                                                  int total4) {
    int i = blockIdx.x * 256 + threadIdx.x;
    if (i >= total4) return;
    float4 v = x4[i];
    xq[i] = make_uchar4(f2fp8(v.x), f2fp8(v.y), f2fp8(v.z), f2fp8(v.w));
}

// -------- gather layer1: agg(x fp8) -> bf16, 32 thr/node x 4 feats ---------
__global__ __launch_bounds__(256) void gather_x_fp8(const unsigned char* __restrict__ xq,
                                                    const int* __restrict__ cnt,
                                                    const int2* __restrict__ csr,
                                                    const int4* __restrict__ ov,
                                                    const int* __restrict__ ov_cnt,
                                                    unsigned short* __restrict__ out) {
    int node = blockIdx.x * 8 + (threadIdx.x >> 5);
    int g = threadIdx.x & 31;
    if (node >= N_NODES) return;
    int beg = node * CAP;
    int end = beg + min(cnt[node], CAP);
    float a[4] = {};
    for (int base = beg; base < end; base += 32) {
        int c = min(32, end - base);
        int sv = 0; float wv = 0.f;
        if (g < c) {
            int2 iv = csr[base + g];
            sv = iv.x; wv = __int_as_float(iv.y);
        }
        int j = 0;
        for (; j + 4 <= c; j += 4) {
            int s0 = __shfl(sv, j, 32),     s1 = __shfl(sv, j + 1, 32);
            int s2 = __shfl(sv, j + 2, 32), s3 = __shfl(sv, j + 3, 32);
            float w0 = __shfl(wv, j, 32),     w1 = __shfl(wv, j + 1, 32);
            float w2 = __shfl(wv, j + 2, 32), w3 = __shfl(wv, j + 3, 32);
            unsigned q0 = *(const unsigned*)(xq + (size_t)s0 * 128 + g * 4);
            unsigned q1 = *(const unsigned*)(xq + (size_t)s1 * 128 + g * 4);
            unsigned q2 = *(const unsigned*)(xq + (size_t)s2 * 128 + g * 4);
            unsigned q3 = *(const unsigned*)(xq + (size_t)s3 * 128 + g * 4);
            float d0[4], d1[4], d2[4], d3[4];
            fp8x4_to_f32x4(q0, d0); fp8x4_to_f32x4(q1, d1);
            fp8x4_to_f32x4(q2, d2); fp8x4_to_f32x4(q3, d3);
#pragma unroll
            for (int t = 0; t < 4; ++t)
                a[t] += d0[t] * w0 + d1[t] * w1 + d2[t] * w2 + d3[t] * w3;
        }
        for (; j < c; ++j) {
            int s0 = __shfl(sv, j, 32);
            float w0 = __shfl(wv, j, 32);
            unsigned q0 = *(const unsigned*)(xq + (size_t)s0 * 128 + g * 4);
            float d0[4];
            fp8x4_to_f32x4(q0, d0);
#pragma unroll
            for (int t = 0; t < 4; ++t) a[t] += d0[t] * w0;
        }
    }
    int L = min(*ov_cnt, OV_CAP);
    for (int i = 0; i < L; ++i) {
        int4 e = ov[i];
        if (e.z == node) {
            float w0 = __int_as_float(e.y);
            unsigned q0 = *(const unsigned*)(xq + (size_t)e.x * 128 + g * 4);
            float d0[4];
            fp8x4_to_f32x4(q0, d0);
#pragma unroll
            for (int t = 0; t < 4; ++t) a[t] += d0[t] * w0;
        }
    }
    ushort4 o = make_ushort4(f2bf(a[0]), f2bf(a[1]), f2bf(a[2]), f2bf(a[3]));
    *(ushort4*)(out + (size_t)node * 128 + g * 4) = o;
}

// ---- gather layer2: agg(h fp8) -> bias+relu -> bf16, 32 thr/node x 8 ------
__global__ __launch_bounds__(256) void gather_h_fp8(const unsigned char* __restrict__ h,
                                                    const int* __restrict__ cnt,
                                                    const int2* __restrict__ csr,
                                                    const int4* __restrict__ ov,
                                                    const int* __restrict__ ov_cnt,
                                                    const float* __restrict__ bias,
                                                    unsigned short* __restrict__ out) {
    int node = blockIdx.x * 8 + (threadIdx.x >> 5);
    int g = threadIdx.x & 31;
    if (node >= N_NODES) return;
    int beg = node * CAP;
    int end = beg + min(cnt[node], CAP);
    float acc[8] = {};
    for (int base = beg; base < end; base += 32) {
        int c = min(32, end - base);
        int sv = 0; float wv = 0.f;
        if (g < c) {
            int2 iv = csr[base + g];
            sv = iv.x; wv = __int_as_float(iv.y);
        }
        int j = 0;
        for (; j + 4 <= c; j += 4) {
            int s0 = __shfl(sv, j, 32),     s1 = __shfl(sv, j + 1, 32);
            int s2 = __shfl(sv, j + 2, 32), s3 = __shfl(sv, j + 3, 32);
            float w0 = __shfl(wv, j, 32),     w1 = __shfl(wv, j + 1, 32);
            float w2 = __shfl(wv, j + 2, 32), w3 = __shfl(wv, j + 3, 32);
            uint2 q0 = *(const uint2*)(h + (size_t)s0 * 256 + g * 8);
            uint2 q1 = *(const uint2*)(h + (size_t)s1 * 256 + g * 8);
            uint2 q2 = *(const uint2*)(h + (size_t)s2 * 256 + g * 8);
            uint2 q3 = *(const uint2*)(h + (size_t)s3 * 256 + g * 8);
            float d0[8], d1[8], d2[8], d3[8];
            fp8x4_to_f32x4(q0.x, d0); fp8x4_to_f32x4(q0.y, d0 + 4);
            fp8x4_to_f32x4(q1.x, d1); fp8x4_to_f32x4(q1.y, d1 + 4);
            fp8x4_to_f32x4(q2.x, d2); fp8x4_to_f32x4(q2.y, d2 + 4);
            fp8x4_to_f32x4(q3.x, d3); fp8x4_to_f32x4(q3.y, d3 + 4);
#pragma unroll
            for (int t = 0; t < 8; ++t)
                acc[t] += d0[t] * w0 + d1[t] * w1 + d2[t] * w2 + d3[t] * w3;
        }
        for (; j < c; ++j) {
            int s0 = __shfl(sv, j, 32);
            float w0 = __shfl(wv, j, 32);
            uint2 q0 = *(const uint2*)(h + (size_t)s0 * 256 + g * 8);
            float d0[8];
            fp8x4_to_f32x4(q0.x, d0); fp8x4_to_f32x4(q0.y, d0 + 4);
#pragma unroll
            for (int t = 0; t < 8; ++t)
                acc[t] += d0[t] * w0;
        }
    }
    int L = min(*ov_cnt, OV_CAP);
    for (int i = 0; i < L; ++i) {
        int4 e = ov[i];
        if (e.z == node) {
            float w0 = __int_as_float(e.y);
            uint2 q0 = *(const uint2*)(h + (size_t)e.x * 256 + g * 8);
            float d0[8];
            fp8x4_to_f32x4(q0.x, d0); fp8x4_to_f32x4(q0.y, d0 + 4);
#pragma unroll
            for (int t = 0; t < 8; ++t) acc[t] += d0[t] * w0;
        }
    }
    short8 ov8;
#pragma unroll
    for (int t = 0; t < 8; ++t) {
        float r = fmaxf(acc[t] + bias[g * 8 + t], 0.f);
        ov8[t] = (short)f2bf(r);
    }
    *(short8*)(out + (size_t)node * 256 + g * 8) = ov8;
}

// --------------- bf16 MFMA GEMM: C[N,M] = A[N,K] @ Wt[M,K]^T ---------------
// BM=128, BN=64, BK=32; 4 waves (2x2). Staging via global_load_lds width=16:
// the XOR bank-swizzle is applied on the GLOBAL address (per-lane vaddr is
// free-form); LDS dest stays linear base+lane*16 as HW requires. OOB rows/cols
// clamp to a valid row — garbage flows only into never-stored C cells.
template <int OUT_MODE>
__global__ __launch_bounds__(256) void mfma_gemm(const short* __restrict__ A,
                                                 const short* __restrict__ Wt,
                                                 void* __restrict__ Cout,
                                                 int N, int K, int M,
                                                 const float* __restrict__ bias,
                                                 int act) {
    __shared__ short As[128 * 32];
    __shared__ short Bs[64 * 32];
    const int tid = threadIdx.x;
    const int lane = tid & 63;
    const int wave = tid >> 6;
    const int wr = wave >> 1, wc = wave & 1;
    const int row0 = blockIdx.y * 128;
    const int col0 = blockIdx.x * 64;

    floatx4 acc[4][2];
#pragma unroll
    for (int t = 0; t < 4; ++t)
#pragma unroll
        for (int u = 0; u < 2; ++u) acc[t][u] = (floatx4){0.f, 0.f, 0.f, 0.f};

    for (int k0 = 0; k0 < K; k0 += 32) {
        // A tile: 512 chunks of 16B; wave w covers [w*128, w*128+128), 2 insts
#pragma unroll
        for (int j = 0; j < 2; ++j) {
            int c = wave * 128 + j * 64 + lane;
            int r = c >> 2, cc = c & 3;
            int gr = min(row0 + r, N - 1);
            const short* gp = A + (size_t)gr * K + k0 + ((cc ^ ((r >> 1) & 3)) << 3);
            __builtin_amdgcn_global_load_lds(
                (glb_void*)gp,
                (lds_void*)(As + (size_t)(wave * 128 + j * 64) * 8), 16, 0, 0);
        }
        // B tile: 256 chunks; wave w covers [w*64, w*64+64), 1 inst
        {
            int c = wave * 64 + lane;
            int r = c >> 2, cc = c & 3;
            int gn = min(col0 + r, M - 1);
            const short* gp = Wt + (size_t)gn * K + k0 + ((cc ^ ((r >> 1) & 3)) << 3);
            __builtin_amdgcn_global_load_lds(
                (glb_void*)gp,
                (lds_void*)(Bs + (size_t)(wave * 64) * 8), 16, 0, 0);
        }
        __syncthreads();

        short8 bf[2];
#pragma unroll
        for (int u = 0; u < 2; ++u) {
            int n = wc * 32 + u * 16 + (lane & 15);
            int ch = (lane >> 4) ^ ((n >> 1) & 3);
            bf[u] = *(const short8*)&Bs[n * 32 + (ch << 3)];
        }
#pragma unroll
        for (int t = 0; t < 4; ++t) {
            int r = wr * 64 + t * 16 + (lane & 15);
            int ch = (lane >> 4) ^ ((r >> 1) & 3);
            short8 af = *(const short8*)&As[r * 32 + (ch << 3)];
            acc[t][0] = __builtin_amdgcn_mfma_f32_16x16x32_bf16(af, bf[0], acc[t][0], 0, 0, 0);
            acc[t][1] = __builtin_amdgcn_mfma_f32_16x16x32_bf16(af, bf[1], acc[t][1], 0, 0, 0);
        }
        __syncthreads();
    }

#pragma unroll
    for (int t = 0; t < 4; ++t) {
#pragma unroll
        for (int u = 0; u < 2; ++u) {
            int gcol = col0 + wc * 32 + u * 16 + (lane & 15);
            if (gcol >= M) continue;
            float bv = bias ? bias[gcol] : 0.f;
#pragma unroll
            for (int reg = 0; reg < 4; ++reg) {
                int grow = row0 + wr * 64 + t * 16 + (lane >> 4) * 4 + reg;
                if (grow >= N) continue;
                float v = acc[t][u][reg] + bv;
                if (act) v = fmaxf(v, 0.f);
                if (OUT_MODE == 1)
                    ((unsigned short*)Cout)[(size_t)grow * M + gcol] = f2bf(v);
                else if (OUT_MODE == 2)
                    ((unsigned char*)Cout)[(size_t)grow * M + gcol] = f2fp8(v);
                else
                    ((float*)Cout)[(size_t)grow * M + gcol] = v;
            }
        }
    }
}

// ---- final: gather bf16 40-wide rows + bias + log_softmax, wave/node ------
__global__ __launch_bounds__(256) void gather_lsm(const unsigned short* __restrict__ h,
                                                  const int* __restrict__ cnt,
                                                  const int2* __restrict__ csr,
                                                  const int4* __restrict__ ov,
                                                  const int* __restrict__ ov_cnt,
                                                  const float* __restrict__ b,
                                                  float* __restrict__ out, int n) {
    int wave = threadIdx.x >> 6;
    int lane = threadIdx.x & 63;
    int node = blockIdx.x * 4 + wave;
    if (node >= n) return;
    int beg = node * CAP;
    int end = beg + min(cnt[node], CAP);
    float acc = 0.f;
    for (int base = beg; base < end; base += 64) {
        int c = min(64, end - base);
        int sv = 0; float wv = 0.f;
        if (lane < c) {
            int2 iv = csr[base + lane];
            sv = iv.x; wv = __int_as_float(iv.y);
        }
        int j = 0;
        for (; j + 4 <= c; j += 4) {
            int s0 = __shfl(sv, j, 64),     s1 = __shfl(sv, j + 1, 64);
            int s2 = __shfl(sv, j + 2, 64), s3 = __shfl(sv, j + 3, 64);
            float w0 = __shfl(wv, j, 64),     w1 = __shfl(wv, j + 1, 64);
            float w2 = __shfl(wv, j + 2, 64), w3 = __shfl(wv, j + 3, 64);
            float v0 = 0.f, v1 = 0.f, v2 = 0.f, v3 = 0.f;
            if (lane < OUT_CH) {
                v0 = bf2f(h[(size_t)s0 * OUT_CH + lane]);
                v1 = bf2f(h[(size_t)s1 * OUT_CH + lane]);
                v2 = bf2f(h[(size_t)s2 * OUT_CH + lane]);
                v3 = bf2f(h[(size_t)s3 * OUT_CH + lane]);
            }
            acc += v0 * w0 + v1 * w1 + v2 * w2 + v3 * w3;
        }
        for (; j < c; ++j) {
            int s0 = __shfl(sv, j, 64);
            float w0 = __shfl(wv, j, 64);
            if (lane < OUT_CH) acc += bf2f(h[(size_t)s0 * OUT_CH + lane]) * w0;
        }
    }
    int L = min(*ov_cnt, OV_CAP);
    for (int i = 0; i < L; ++i) {
        int4 e = ov[i];
        if (e.z == node && lane < OUT_CH)
            acc += bf2f(h[(size_t)e.x * OUT_CH + lane]) * __int_as_float(e.y);
    }
    float val = 0.f, v = -INFINITY;
    if (lane < OUT_CH) {
        val = acc + b[lane];
        v = val;
    }
#pragma unroll
    for (int off = 32; off; off >>= 1)
        v = fmaxf(v, __shfl_xor(v, off, 64));
    float ex = (lane < OUT_CH) ? expf(val - v) : 0.f;
#pragma unroll
    for (int off = 32; off; off >>= 1)
        ex += __shfl_xor(ex, off, 64);
    float ls = logf(ex);
    if (lane < OUT_CH) out[(size_t)node * OUT_CH + lane] = val - v - ls;
}

// ---------------------------------------------------------------------------
extern "C" void kernel_launch(void* const* d_in, const int* in_sizes, int n_in,
                              void* d_out, int out_size, void* d_ws, size_t ws_size,
                              hipStream_t stream) {
    const float* x   = (const float*)d_in[0];
    const int*  eidx = (const int*)d_in[1];
    const float* ew  = (const float*)d_in[2];
    const float* W1  = (const float*)d_in[3];
    const float* b1  = (const float*)d_in[4];
    const float* W2  = (const float*)d_in[5];
    const float* b2  = (const float*)d_in[6];
    const float* W3  = (const float*)d_in[7];
    const float* b3  = (const float*)d_in[8];
    const int* src = eidx;
    const int* dst = eidx + N_EDGES;
    float* out = (float*)d_out;

    short* region0 = (short*)d_ws;                          // xq(fp8) / h2p(fp8)
    short* region1 = region0 + (size_t)N_NODES * HID;       // aggX / h3p
    short* H1   = region1 + (size_t)N_NODES * IN_CH;
    short* H2   = H1 + (size_t)N_NODES * HID;
    short* Wt1  = H2 + (size_t)N_NODES * HID;
    short* Wt2  = Wt1 + HID * IN_CH;
    short* Wt3  = Wt2 + HID * HID;
    int*   cnt     = (int*)(Wt3 + OUT_CH * HID);            // N_NODES + ov_cnt
    int*   ov_cnt  = cnt + N_NODES;
    int2*  csr     = (int2*)(cnt + N_NODES + 2);            // N_NODES*CAP int2
    int4*  ovbuf   = (int4*)(csr + (size_t)N_NODES * CAP);  // OV_CAP int4

    unsigned char* xq  = (unsigned char*)region0;           // fp8, 6.4 MB
    unsigned char* h2p = (unsigned char*)region0;           // fp8, 12.8 MB
    short* aggX = region1;
    short* h3p  = region1;

    dim3 blk(256);

    // ---- CSR build: one memset + one edge pass (fixed slots, r12 structure)
    hipMemsetAsync(cnt, 0, (N_NODES + 1) * sizeof(int), stream);
    fill_fixed<<<NCHUNK * PARTS, blk, 0, stream>>>(src, dst, ew, cnt, csr, ovbuf, ov_cnt);

    // ---- weight + x casts
    {
        int tot = IN_CH * HID + HID * HID + HID * OUT_CH;
        wt_cast_all<<<(tot + 255) / 256, blk, 0, stream>>>(W1, W2, W3, Wt1, Wt2, Wt3);
    }
    cast_x_fp8<<<(N_NODES * IN_CH / 4 + 255) / 256, blk, 0, stream>>>(
        (const float4*)x, (uchar4*)xq, N_NODES * IN_CH / 4);

    // ---- layer 1 (swapped): aggX = gather(xq); H1 = relu(aggX@W1 + b1)
    gather_x_fp8<<<(N_NODES + 7) / 8, blk, 0, stream>>>(
        xq, cnt, csr, ovbuf, ov_cnt, (unsigned short*)aggX);
    {
        dim3 grid((HID + 63) / 64, (N_NODES + 127) / 128);
        mfma_gemm<1><<<grid, blk, 0, stream>>>(aggX, Wt1, H1, N_NODES, IN_CH, HID, b1, 1);
    }

    // ---- layer 2: h2p = fp8(H1@W2) ; H2 = relu(gather(h2p) + b2)
    {
        dim3 grid((HID + 63) / 64, (N_NODES + 127) / 128);
        mfma_gemm<2><<<grid, blk, 0, stream>>>(H1, Wt2, h2p, N_NODES, HID, HID, nullptr, 0);
    }
    gather_h_fp8<<<(N_NODES + 7) / 8, blk, 0, stream>>>(
        h2p, cnt, csr, ovbuf, ov_cnt, b2, (unsigned short*)H2);

    // ---- layer 3: h3p = H2@W3 (bf16) ; out = log_softmax(gather(h3p) + b3)
    {
        dim3 grid((OUT_CH + 63) / 64, (N_NODES + 127) / 128);
        mfma_gemm<1><<<grid, blk, 0, stream>>>(H2, Wt3, h3p, N_NODES, HID, OUT_CH, nullptr, 0);
    }
    gather_lsm<<<(N_NODES + 3) / 4, blk, 0, stream>>>(
        (const unsigned short*)h3p, cnt, csr, ovbuf, ov_cnt, b3, out, N_NODES);
}